// Round 5
// baseline (40.038 us; speedup 1.0000x reference)
//
#include <hip/hip_runtime.h>
#include <math.h>

// Geometry (fixed): 256 x 8192 x 3 f32 per input = 2,097,152 rows of 3.
#define N_ROWS   (256 * 8192)
#define BLOCK    256
#define ROWS_PER_THREAD 4
#define GRID     (N_ROWS / (BLOCK * ROWS_PER_THREAD))   // 2048
#define F4_PER_BLOCK (BLOCK * 3)                        // 768 float4 per input

// XOR swizzle on float4 index: conflict-free for both the unit-stride writes
// and the stride-3 reads (3 coprime to 8 -> alias sets cover all bank groups).
__device__ __forceinline__ int swz(int j) { return j ^ ((j >> 3) & 7); }

// Branchless acos, |err| < 6.8e-5 rad (Abramowitz-Stegun 4.4.45).
__device__ __forceinline__ float acos_fast(float x) {
    float ax = fabsf(x);
    float s  = sqrtf(fmaxf(0.0f, 1.0f - ax));
    float p  = fmaf(ax, -0.0187293f, 0.0742610f);
    p = fmaf(ax, p, -0.2121144f);
    p = fmaf(ax, p, 1.5707288f);
    float r = s * p;
    return (x >= 0.0f) ? r : (3.14159265358979f - r);
}

__global__ __launch_bounds__(BLOCK) void angle_main(
    const float* __restrict__ o,
    const float* __restrict__ t,
    float* __restrict__ out)
{
    __shared__ float4 so[F4_PER_BLOCK];
    __shared__ float4 st[F4_PER_BLOCK];

    const int tx  = threadIdx.x;
    const int bid = blockIdx.x;
    const long base4 = (long)bid * F4_PER_BLOCK;
    const float4* o4 = reinterpret_cast<const float4*>(o);
    const float4* t4 = reinterpret_cast<const float4*>(t);

    // Unit-stride coalesced global loads, swizzled LDS store.
#pragma unroll
    for (int k = 0; k < 3; ++k) {
        int j = k * BLOCK + tx;
        so[swz(j)] = o4[base4 + j];
        st[swz(j)] = t4[base4 + j];
    }
    __syncthreads();

    // Each thread: 12 contiguous floats = 4 rows of 3, via swizzled reads.
    float4 a0 = so[swz(3 * tx + 0)];
    float4 a1 = so[swz(3 * tx + 1)];
    float4 a2 = so[swz(3 * tx + 2)];
    float4 b0 = st[swz(3 * tx + 0)];
    float4 b1 = st[swz(3 * tx + 1)];
    float4 b2 = st[swz(3 * tx + 2)];

    float ox[4] = {a0.x, a0.w, a1.z, a2.y};
    float oy[4] = {a0.y, a1.x, a1.w, a2.z};
    float oz[4] = {a0.z, a1.y, a2.x, a2.w};
    float tx_[4] = {b0.x, b0.w, b1.z, b2.y};
    float ty_[4] = {b0.y, b1.x, b1.w, b2.z};
    float tz_[4] = {b0.z, b1.y, b2.x, b2.w};

    float s = 0.0f;
#pragma unroll
    for (int r = 0; r < 4; ++r) {
        float dot = ox[r] * tx_[r] + oy[r] * ty_[r] + oz[r] * tz_[r];
        float no2 = ox[r] * ox[r] + oy[r] * oy[r] + oz[r] * oz[r];
        float nt2 = tx_[r] * tx_[r] + ty_[r] * ty_[r] + tz_[r] * tz_[r];
        float c = dot * rsqrtf(no2) * rsqrtf(nt2);
        c = fminf(1.0f, fmaxf(-1.0f, c));
        s += acos_fast(c);
    }

    // Wave (64) reduce, then block reduce.
#pragma unroll
    for (int off = 32; off > 0; off >>= 1)
        s += __shfl_down(s, off, 64);

    __shared__ float waves[BLOCK / 64];
    const int lane = tx & 63;
    const int wid  = tx >> 6;
    if (lane == 0) waves[wid] = s;
    __syncthreads();

    if (tx == 0) {
        float bs = 0.0f;
#pragma unroll
        for (int w = 0; w < BLOCK / 64; ++w) bs += waves[w];
        // One relaxed hardware f32 atomic per block (2048 total), agent scope,
        // NO fences (round 2's ACQ_REL+threadfence cost 5.6x). d_out is
        // re-zeroed by the memset node at the start of every replay.
        __hip_atomic_fetch_add(out, bs * (1.0f / (float)N_ROWS),
                               __ATOMIC_RELAXED, __HIP_MEMORY_SCOPE_AGENT);
    }
}

extern "C" void kernel_launch(void* const* d_in, const int* in_sizes, int n_in,
                              void* d_out, int out_size, void* d_ws, size_t ws_size,
                              hipStream_t stream)
{
    const float* outputs = (const float*)d_in[0];
    const float* targets = (const float*)d_in[1];
    float* out = (float*)d_out;

    hipMemsetAsync(out, 0, sizeof(float), stream);  // graph-capturable node
    angle_main<<<GRID, BLOCK, 0, stream>>>(outputs, targets, out);
}

// Round 6
// 16.531 us; speedup vs baseline: 2.4220x; 2.4220x over previous
//
#include <hip/hip_runtime.h>
#include <math.h>

// Geometry (fixed): 256 x 8192 x 3 f32 per input = 2,097,152 rows of 3.
#define N_ROWS   (256 * 8192)
#define BLOCK    256
#define ROWS_PER_THREAD 8
#define GRID     (N_ROWS / (BLOCK * ROWS_PER_THREAD))   // 1024
#define F4_PER_THREAD 6                                 // 6 float4 = 8 rows
#define F4_PER_BLOCK (BLOCK * F4_PER_THREAD)            // 1536 per input (24 KB)

// XOR swizzle on float4 index within 8-float4 (128 B) groups: conflict-free
// for unit-stride writes; stride-6 reads land 2-way max (free per HW).
__device__ __forceinline__ int swz(int j) { return j ^ ((j >> 3) & 7); }

// Branchless acos, |err| < 6.8e-5 rad (Abramowitz-Stegun 4.4.45).
__device__ __forceinline__ float acos_fast(float x) {
    float ax = fabsf(x);
    float s  = sqrtf(fmaxf(0.0f, 1.0f - ax));
    float p  = fmaf(ax, -0.0187293f, 0.0742610f);
    p = fmaf(ax, p, -0.2121144f);
    p = fmaf(ax, p, 1.5707288f);
    float r = s * p;
    return (x >= 0.0f) ? r : (3.14159265358979f - r);
}

// 3 float4 (= 4 rows of 3 floats) from each input -> sum of 4 angles.
__device__ __forceinline__ float rows4(float4 a0, float4 a1, float4 a2,
                                       float4 b0, float4 b1, float4 b2) {
    float ox[4] = {a0.x, a0.w, a1.z, a2.y};
    float oy[4] = {a0.y, a1.x, a1.w, a2.z};
    float oz[4] = {a0.z, a1.y, a2.x, a2.w};
    float txv[4] = {b0.x, b0.w, b1.z, b2.y};
    float tyv[4] = {b0.y, b1.x, b1.w, b2.z};
    float tzv[4] = {b0.z, b1.y, b2.x, b2.w};
    float s = 0.0f;
#pragma unroll
    for (int r = 0; r < 4; ++r) {
        float dot = ox[r] * txv[r] + oy[r] * tyv[r] + oz[r] * tzv[r];
        float no2 = ox[r] * ox[r] + oy[r] * oy[r] + oz[r] * oz[r];
        float nt2 = txv[r] * txv[r] + tyv[r] * tyv[r] + tzv[r] * tzv[r];
        float c = dot * rsqrtf(no2) * rsqrtf(nt2);
        c = fminf(1.0f, fmaxf(-1.0f, c));
        s += acos_fast(c);
    }
    return s;
}

__global__ __launch_bounds__(BLOCK) void angle_partial(
    const float* __restrict__ o,
    const float* __restrict__ t,
    float* __restrict__ partial)
{
    __shared__ float4 so[F4_PER_BLOCK];   // 24 KB
    __shared__ float4 st[F4_PER_BLOCK];   // 24 KB

    const int tx  = threadIdx.x;
    const int bid = blockIdx.x;
    const long base4 = (long)bid * F4_PER_BLOCK;
    const float4* o4 = reinterpret_cast<const float4*>(o);
    const float4* t4 = reinterpret_cast<const float4*>(t);

    // Phase 1: issue all 12 independent unit-stride global loads (192 B
    // in flight per thread), THEN write LDS -- maximizes overlap.
    float4 ra[F4_PER_THREAD], rb[F4_PER_THREAD];
#pragma unroll
    for (int k = 0; k < F4_PER_THREAD; ++k) ra[k] = o4[base4 + k * BLOCK + tx];
#pragma unroll
    for (int k = 0; k < F4_PER_THREAD; ++k) rb[k] = t4[base4 + k * BLOCK + tx];
#pragma unroll
    for (int k = 0; k < F4_PER_THREAD; ++k) so[swz(k * BLOCK + tx)] = ra[k];
#pragma unroll
    for (int k = 0; k < F4_PER_THREAD; ++k) st[swz(k * BLOCK + tx)] = rb[k];
    __syncthreads();

    // Phase 2: each thread consumes 24 contiguous floats = 8 rows of 3.
    float4 a0 = so[swz(6 * tx + 0)];
    float4 a1 = so[swz(6 * tx + 1)];
    float4 a2 = so[swz(6 * tx + 2)];
    float4 a3 = so[swz(6 * tx + 3)];
    float4 a4 = so[swz(6 * tx + 4)];
    float4 a5 = so[swz(6 * tx + 5)];
    float4 b0 = st[swz(6 * tx + 0)];
    float4 b1 = st[swz(6 * tx + 1)];
    float4 b2 = st[swz(6 * tx + 2)];
    float4 b3 = st[swz(6 * tx + 3)];
    float4 b4 = st[swz(6 * tx + 4)];
    float4 b5 = st[swz(6 * tx + 5)];

    float s = rows4(a0, a1, a2, b0, b1, b2)
            + rows4(a3, a4, a5, b3, b4, b5);

    // Wave (64) reduce, then block reduce. No fences, no atomics:
    // the kernel boundary is the device-wide sync.
#pragma unroll
    for (int off = 32; off > 0; off >>= 1)
        s += __shfl_down(s, off, 64);

    __shared__ float waves[BLOCK / 64];
    const int lane = tx & 63;
    const int wid  = tx >> 6;
    if (lane == 0) waves[wid] = s;
    __syncthreads();

    if (tx == 0) {
        float bs = 0.0f;
#pragma unroll
        for (int w = 0; w < BLOCK / 64; ++w) bs += waves[w];
        partial[bid] = bs;
    }
}

__global__ __launch_bounds__(BLOCK) void angle_final(
    const float* __restrict__ partial,
    float* __restrict__ out)
{
    // 1024 partials = 256 float4: exactly one vector load per thread.
    const float4* p4 = reinterpret_cast<const float4*>(partial);
    float4 v = p4[threadIdx.x];
    float s = v.x + v.y + v.z + v.w;

#pragma unroll
    for (int off = 32; off > 0; off >>= 1)
        s += __shfl_down(s, off, 64);

    __shared__ float waves[BLOCK / 64];
    const int lane = threadIdx.x & 63;
    const int wid  = threadIdx.x >> 6;
    if (lane == 0) waves[wid] = s;
    __syncthreads();

    if (threadIdx.x == 0) {
        float total = 0.0f;
#pragma unroll
        for (int w = 0; w < BLOCK / 64; ++w) total += waves[w];
        out[0] = total / (float)N_ROWS;
    }
}

extern "C" void kernel_launch(void* const* d_in, const int* in_sizes, int n_in,
                              void* d_out, int out_size, void* d_ws, size_t ws_size,
                              hipStream_t stream)
{
    const float* outputs = (const float*)d_in[0];
    const float* targets = (const float*)d_in[1];
    float* out = (float*)d_out;
    float* partial = (float*)d_ws;  // 4 KB scratch

    angle_partial<<<GRID, BLOCK, 0, stream>>>(outputs, targets, partial);
    angle_final<<<1, BLOCK, 0, stream>>>(partial, out);
}